// Round 3
// baseline (255.348 us; speedup 1.0000x reference)
//
#include <hip/hip_runtime.h>
#include <stdint.h>
#include <math.h>

#define BB 4
#define HH 512
#define WW 512
#define HWW (HH*WW)      // 262144
#define CC 128
#define KK 512
#define SELCAP 2048

#define TILE 64
#define HALO 15
#define TS 94            // TILE + 2*HALO
#define SW 96            // padded LDS stride
#define NT 1024
#define TCAP 512         // per-tile candidate slot (max real ~289)

__device__ __forceinline__ float colmax7(const float* __restrict__ p, int o){
    return fmaxf(fmaxf(fmaxf(p[o-3*SW], p[o-2*SW]), fmaxf(p[o-SW], p[o])),
                 fmaxf(fmaxf(p[o+SW], p[o+2*SW]), p[o+3*SW]));
}

// One block = one 64x64 output tile (+15 halo). Entire 2-iteration NMS in LDS.
// Survivors go to a fixed per-tile segment: cs/ci[(b*64+t)*TCAP ...], count in cnt[b*64+t].
// No global atomics, no init required (every slot we read is written this call).
__global__ __launch_bounds__(NT) void nms_fused_k(const float* __restrict__ sc,
                                                  float* __restrict__ cs, int* __restrict__ ci,
                                                  int* __restrict__ cnt){
    __shared__ float S[TS*SW];
    __shared__ float A[TS*SW];
    __shared__ float Bf[TS*SW];
    __shared__ unsigned char M[TS*SW];
    __shared__ unsigned char T[TS*SW];
    __shared__ unsigned char P[TS*SW];
    __shared__ float lsc[TCAP];
    __shared__ int   lidx[TCAP];
    __shared__ int   lcnt;

    const int tid = threadIdx.x;
    const int bb = blockIdx.x >> 6;          // batch
    const int t  = blockIdx.x & 63;
    const int ty = t >> 3, tx = t & 7;
    const int oy = ty * TILE - HALO, ox = tx * TILE - HALO;
    const float* sb = sc + (size_t)bb * HWW;

    if (tid == 0) lcnt = 0;

    // ---- load scores (out-of-image = -inf, matching reduce_window pad) ----
    for (int i = tid; i < TS*TS; i += NT){
        int y = i / TS, x = i - y * TS;
        int gy = oy + y, gx = ox + x;
        float v = -INFINITY;
        if ((unsigned)gy < (unsigned)HH && (unsigned)gx < (unsigned)WW)
            v = sb[(gy << 9) + gx];
        S[y*SW + x] = v;
    }
    __syncthreads();

#define ROWMAX(dst, src, Y0, Y1, X0, X1)                                   \
    for (int i = tid; i < (Y1-Y0)*(X1-X0); i += NT){                        \
        int y = (Y0) + i / (X1-X0), x = (X0) + i % (X1-X0);                 \
        int o = y*SW + x;                                                   \
        dst[o] = fmaxf(fmaxf(fmaxf(src[o-3],src[o-2]),fmaxf(src[o-1],src[o])), \
                       fmaxf(fmaxf(src[o+1],src[o+2]),src[o+3]));           \
    }                                                                       \
    __syncthreads();

#define ROWOR(dst, src, Y0, Y1, X0, X1)                                    \
    for (int i = tid; i < (Y1-Y0)*(X1-X0); i += NT){                        \
        int y = (Y0) + i / (X1-X0), x = (X0) + i % (X1-X0);                 \
        int o = y*SW + x;                                                   \
        dst[o] = (unsigned char)(src[o-3]|src[o-2]|src[o-1]|src[o]|         \
                                 src[o+1]|src[o+2]|src[o+3]);               \
    }                                                                       \
    __syncthreads();

// col-OR of T -> P (supp mask); A = supp ? 0 : S (out-of-image stays -inf)
#define COLSUPP(Y0, Y1)                                                     \
    for (int i = tid; i < (Y1-Y0)*(Y1-Y0); i += NT){                        \
        int y = (Y0) + i / (Y1-Y0), x = (Y0) + i % (Y1-Y0);                 \
        int o = y*SW + x;                                                   \
        unsigned char v = (unsigned char)(T[o-3*SW]|T[o-2*SW]|T[o-SW]|T[o]| \
                                          T[o+SW]|T[o+2*SW]|T[o+3*SW]);     \
        P[o] = v;                                                           \
        bool in = ((unsigned)(oy+y) < (unsigned)HH) &&                      \
                  ((unsigned)(ox+x) < (unsigned)WW);                        \
        A[o] = (!in) ? -INFINITY : (v ? 0.0f : S[o]);                       \
    }                                                                       \
    __syncthreads();

    // ---- M0 = (s == pool7(s)) ----
    ROWMAX(A, S, 0, 94, 3, 91)
    for (int i = tid; i < 88*88; i += NT){
        int y = 3 + i / 88, x = 3 + i % 88;
        int o = y*SW + x;
        float cm = colmax7(A, o);
        bool in = ((unsigned)(oy+y) < (unsigned)HH) && ((unsigned)(ox+x) < (unsigned)WW);
        M[o] = (in && S[o] == cm) ? 1 : 0;
    }
    __syncthreads();

    // ---- iteration 1 ----
    ROWOR(T, M, 3, 91, 6, 88)
    COLSUPP(6, 88)                       // P = supp1, A = ss1
    ROWMAX(Bf, A, 6, 88, 9, 85)
    for (int i = tid; i < 76*76; i += NT){   // M |= (ss==pool(ss)) & ~supp
        int y = 9 + i / 76, x = 9 + i % 76;
        int o = y*SW + x;
        float cm = colmax7(Bf, o);
        bool in = ((unsigned)(oy+y) < (unsigned)HH) && ((unsigned)(ox+x) < (unsigned)WW);
        if (in && A[o] == cm && !P[o]) M[o] = 1;
    }
    __syncthreads();

    // ---- iteration 2 ----
    ROWOR(T, M, 9, 85, 12, 82)
    COLSUPP(12, 82)                      // P = supp2, A = ss2
    ROWMAX(Bf, A, 12, 82, 15, 79)

    // ---- final mask + per-block compaction ----
    for (int i = tid; i < TILE*TILE; i += NT){
        int y = HALO + (i >> 6), x = HALO + (i & 63);
        int o = y*SW + x;
        float cm = colmax7(Bf, o);
        float sv = S[o];
        bool fm = M[o] || ((A[o] == cm) && !P[o]);
        if (fm && sv > 0.0f){
            int p = atomicAdd(&lcnt, 1);
            if (p < TCAP){ lsc[p] = sv; lidx[p] = ((oy+y) << 9) + (ox+x); }
        }
    }
    __syncthreads();
    int nl = lcnt; if (nl > TCAP) nl = TCAP;
    const int seg = bb * 64 + t;
    if (tid == 0) cnt[seg] = nl;
    float* os = cs + (size_t)seg * TCAP;
    int*   oi = ci + (size_t)seg * TCAP;
    for (int i = tid; i < nl; i += NT){ os[i] = lsc[i]; oi[i] = lidx[i]; }
}

// ---------------- per-batch top-K + gather ----------------

#define NT2 1024

__global__ __launch_bounds__(NT2) void finalize_k(
        const float* __restrict__ cs, const int* __restrict__ ci, const int* __restrict__ cnt,
        const float* __restrict__ points, const float* __restrict__ feat,
        float* __restrict__ out){
    __shared__ int segc[64];
    __shared__ int hist[256];
    __shared__ unsigned long long keys[SELCAP];
    __shared__ int sidx[KK];
    __shared__ unsigned int sh_prefix;
    __shared__ int sh_kneed;
    __shared__ int sh_n;
    __shared__ int selCnt;

    int b = blockIdx.x, tid = threadIdx.x;

    if (tid < 64){ int c = cnt[b*64 + tid]; segc[tid] = (c > TCAP) ? TCAP : c; }
    __syncthreads();
    if (tid == 0){ int s = 0; for (int i = 0; i < 64; ++i) s += segc[i]; sh_n = s; selCnt = 0; }
    __syncthreads();
    int n = sh_n;

    // exact K-th largest via 4x8-bit radix select on float bits (all scores > 0)
    unsigned int Tbits = 1u;
    if (n >= KK){
        unsigned int prefix = 0; int kneed = KK;
        for (int r = 0; r < 4; ++r){
            int shift = 24 - 8 * r;
            for (int i = tid; i < 256; i += NT2) hist[i] = 0;
            __syncthreads();
            for (int s = 0; s < 64; ++s){
                const float* ps = cs + (size_t)(b*64 + s) * TCAP;
                int c = segc[s];
                for (int i = tid; i < c; i += NT2){
                    unsigned int bits = __float_as_uint(ps[i]);
                    if (r == 0 || (bits >> (shift + 8)) == prefix)
                        atomicAdd(&hist[(bits >> shift) & 255], 1);
                }
            }
            __syncthreads();
            if (tid == 0){
                int cum = 0, d = 255;
                for (; d >= 0; --d){ cum += hist[d]; if (cum >= kneed) break; }
                if (d < 0) d = 0;
                sh_kneed = kneed - (cum - hist[d]);
                sh_prefix = (prefix << 8) | (unsigned int)d;
            }
            __syncthreads();
            prefix = sh_prefix; kneed = sh_kneed;
            __syncthreads();
        }
        Tbits = prefix;
    }

    // collect all candidates with score >= T
    for (int s = 0; s < 64; ++s){
        const float* ps = cs + (size_t)(b*64 + s) * TCAP;
        const int*   pi = ci + (size_t)(b*64 + s) * TCAP;
        int c = segc[s];
        for (int i = tid; i < c; i += NT2){
            unsigned int bits = __float_as_uint(ps[i]);
            if (bits >= Tbits){
                int p = atomicAdd(&selCnt, 1);
                if (p < SELCAP)
                    keys[p] = ((unsigned long long)bits << 32) | (unsigned int)(~pi[i]);
            }
        }
    }
    __syncthreads();
    int ns = selCnt; if (ns > SELCAP) ns = SELCAP;
    int P2 = 2; while (P2 < ns) P2 <<= 1;
    for (int i = tid; i < P2; i += NT2) if (i >= ns) keys[i] = 0ull;
    __syncthreads();

    // bitonic sort descending by (score_bits, ~idx)  => score desc, idx asc
    for (int k = 2; k <= P2; k <<= 1){
        for (int j = k >> 1; j > 0; j >>= 1){
            for (int i = tid; i < P2; i += NT2){
                int partner = i ^ j;
                if (partner > i){
                    unsigned long long a = keys[i], c = keys[partner];
                    bool asc = ((i & k) != 0);
                    if ((a < c) != asc){ keys[i] = c; keys[partner] = a; }
                }
            }
            __syncthreads();
        }
    }

    for (int k = tid; k < KK; k += NT2){
        int idx = 0;
        if (k < ns) idx = (int)(~(unsigned int)(keys[k] & 0xFFFFFFFFull));
        sidx[k] = idx;
    }
    __syncthreads();
    if (ns < KK && tid == 0){
        // fallback (unreachable with real data): fill with smallest indices not
        // present among candidates (flat==-1 ties break by index asc)
        int fill = ns;
        for (int idx = 0; idx < HWW && fill < KK; ++idx){
            bool inCand = false;
            for (int s = 0; s < 64 && !inCand; ++s){
                const int* pi = ci + (size_t)(b*64 + s) * TCAP;
                int c = segc[s];
                for (int i = 0; i < c; ++i) if (pi[i] == idx){ inCand = true; break; }
            }
            if (!inCand) sidx[fill++] = idx;
        }
    }
    __syncthreads();

    // outputs: kpts (B,K,4) | feas (B,C,K) | pixels (B,K,2)
    const float* pb = points + (size_t)b * 4 * HWW;
    float* out0 = out + (size_t)b * KK * 4;
    float* out2 = out + (size_t)(BB * KK * 4 + BB * CC * KK) + (size_t)b * KK * 2;
    for (int k = tid; k < KK; k += NT2){
        int idx = sidx[k];
        out0[k * 4 + 0] = pb[idx];
        out0[k * 4 + 1] = pb[HWW + idx];
        out0[k * 4 + 2] = 0.0f;
        out0[k * 4 + 3] = 1.0f;
        out2[k * 2 + 0] = (float)(idx >> 9);       // u = idx // W
        out2[k * 2 + 1] = (float)(idx & (WW - 1)); // v = idx % W
    }
    const float* fb = feat + (size_t)b * CC * HWW;
    float* out1 = out + (size_t)(BB * KK * 4) + (size_t)b * CC * KK;
    for (int j = tid; j < CC * KK; j += NT2){
        int c = j >> 9;          // KK = 512
        int k = j & (KK - 1);
        out1[c * KK + k] = fb[(size_t)c * HWW + sidx[k]];
    }
}

extern "C" void kernel_launch(void* const* d_in, const int* in_sizes, int n_in,
                              void* d_out, int out_size, void* d_ws, size_t ws_size,
                              hipStream_t stream) {
    const float* s    = (const float*)d_in[0];  // score_bev  (B,1,H,W)
    const float* feat = (const float*)d_in[1];  // feature_bev(B,C,H,W)
    const float* pts  = (const float*)d_in[2];  // points     (B,4,H,W)
    float* out = (float*)d_out;

    char* w = (char*)d_ws;
    float* cs  = (float*)w;  w += (size_t)BB * 64 * TCAP * 4;
    int*   ci  = (int*)w;    w += (size_t)BB * 64 * TCAP * 4;
    int*   cnt = (int*)w;    w += (size_t)BB * 64 * 4;

    nms_fused_k<<<BB * 64, NT, 0, stream>>>(s, cs, ci, cnt);
    finalize_k<<<BB, NT2, 0, stream>>>(cs, ci, cnt, pts, feat, out);
}

// Round 4
// 107.130 us; speedup vs baseline: 2.3835x; 2.3835x over previous
//
#include <hip/hip_runtime.h>
#include <stdint.h>
#include <math.h>

#define BB 4
#define HH 512
#define WW 512
#define HWW (HH*WW)      // 262144
#define CC 128
#define KK 512
#define SELCAP 2048
#define NCAP 18496       // 64 tiles * 289 max survivors per tile (Chebyshev >=4 spacing)

#define TILE 64
#define HALO 15
#define TS 94            // TILE + 2*HALO
#define SW 96            // padded LDS stride
#define NT 1024
#define TCAP 512         // per-tile candidate slots (max real 289)

__device__ __forceinline__ float colmax7(const float* __restrict__ p, int o){
    return fmaxf(fmaxf(fmaxf(p[o-3*SW], p[o-2*SW]), fmaxf(p[o-SW], p[o])),
                 fmaxf(fmaxf(p[o+SW], p[o+2*SW]), p[o+3*SW]));
}

// One block = one 64x64 output tile (+15 halo). Entire 2-iteration NMS in LDS.
// Survivors go to a fixed per-tile segment; count in cnt[b*64+t]. No global atomics.
__global__ __launch_bounds__(NT) void nms_fused_k(const float* __restrict__ sc,
                                                  float* __restrict__ cs, int* __restrict__ ci,
                                                  int* __restrict__ cnt){
    __shared__ float S[TS*SW];
    __shared__ float A[TS*SW];
    __shared__ float Bf[TS*SW];
    __shared__ unsigned char M[TS*SW];
    __shared__ unsigned char T[TS*SW];
    __shared__ unsigned char P[TS*SW];
    __shared__ float lsc[TCAP];
    __shared__ int   lidx[TCAP];
    __shared__ int   lcnt;

    const int tid = threadIdx.x;
    const int bb = blockIdx.x >> 6;          // batch
    const int t  = blockIdx.x & 63;
    const int ty = t >> 3, tx = t & 7;
    const int oy = ty * TILE - HALO, ox = tx * TILE - HALO;
    const float* sb = sc + (size_t)bb * HWW;

    if (tid == 0) lcnt = 0;

    for (int i = tid; i < TS*TS; i += NT){
        int y = i / TS, x = i - y * TS;
        int gy = oy + y, gx = ox + x;
        float v = -INFINITY;
        if ((unsigned)gy < (unsigned)HH && (unsigned)gx < (unsigned)WW)
            v = sb[(gy << 9) + gx];
        S[y*SW + x] = v;
    }
    __syncthreads();

#define ROWMAX(dst, src, Y0, Y1, X0, X1)                                   \
    for (int i = tid; i < (Y1-Y0)*(X1-X0); i += NT){                        \
        int y = (Y0) + i / (X1-X0), x = (X0) + i % (X1-X0);                 \
        int o = y*SW + x;                                                   \
        dst[o] = fmaxf(fmaxf(fmaxf(src[o-3],src[o-2]),fmaxf(src[o-1],src[o])), \
                       fmaxf(fmaxf(src[o+1],src[o+2]),src[o+3]));           \
    }                                                                       \
    __syncthreads();

#define ROWOR(dst, src, Y0, Y1, X0, X1)                                    \
    for (int i = tid; i < (Y1-Y0)*(X1-X0); i += NT){                        \
        int y = (Y0) + i / (X1-X0), x = (X0) + i % (X1-X0);                 \
        int o = y*SW + x;                                                   \
        dst[o] = (unsigned char)(src[o-3]|src[o-2]|src[o-1]|src[o]|         \
                                 src[o+1]|src[o+2]|src[o+3]);               \
    }                                                                       \
    __syncthreads();

#define COLSUPP(Y0, Y1)                                                     \
    for (int i = tid; i < (Y1-Y0)*(Y1-Y0); i += NT){                        \
        int y = (Y0) + i / (Y1-Y0), x = (Y0) + i % (Y1-Y0);                 \
        int o = y*SW + x;                                                   \
        unsigned char v = (unsigned char)(T[o-3*SW]|T[o-2*SW]|T[o-SW]|T[o]| \
                                          T[o+SW]|T[o+2*SW]|T[o+3*SW]);     \
        P[o] = v;                                                           \
        bool in = ((unsigned)(oy+y) < (unsigned)HH) &&                      \
                  ((unsigned)(ox+x) < (unsigned)WW);                        \
        A[o] = (!in) ? -INFINITY : (v ? 0.0f : S[o]);                       \
    }                                                                       \
    __syncthreads();

    // M0 = (s == pool7(s))
    ROWMAX(A, S, 0, 94, 3, 91)
    for (int i = tid; i < 88*88; i += NT){
        int y = 3 + i / 88, x = 3 + i % 88;
        int o = y*SW + x;
        float cm = colmax7(A, o);
        bool in = ((unsigned)(oy+y) < (unsigned)HH) && ((unsigned)(ox+x) < (unsigned)WW);
        M[o] = (in && S[o] == cm) ? 1 : 0;
    }
    __syncthreads();

    // iteration 1
    ROWOR(T, M, 3, 91, 6, 88)
    COLSUPP(6, 88)
    ROWMAX(Bf, A, 6, 88, 9, 85)
    for (int i = tid; i < 76*76; i += NT){
        int y = 9 + i / 76, x = 9 + i % 76;
        int o = y*SW + x;
        float cm = colmax7(Bf, o);
        bool in = ((unsigned)(oy+y) < (unsigned)HH) && ((unsigned)(ox+x) < (unsigned)WW);
        if (in && A[o] == cm && !P[o]) M[o] = 1;
    }
    __syncthreads();

    // iteration 2
    ROWOR(T, M, 9, 85, 12, 82)
    COLSUPP(12, 82)
    ROWMAX(Bf, A, 12, 82, 15, 79)

    // final mask + per-block compaction
    for (int i = tid; i < TILE*TILE; i += NT){
        int y = HALO + (i >> 6), x = HALO + (i & 63);
        int o = y*SW + x;
        float cm = colmax7(Bf, o);
        float sv = S[o];
        bool fm = M[o] || ((A[o] == cm) && !P[o]);
        if (fm && sv > 0.0f){
            int p = atomicAdd(&lcnt, 1);
            if (p < TCAP){ lsc[p] = sv; lidx[p] = ((oy+y) << 9) + (ox+x); }
        }
    }
    __syncthreads();
    int nl = lcnt; if (nl > TCAP) nl = TCAP;
    const int seg = bb * 64 + t;
    if (tid == 0) cnt[seg] = nl;
    float* os = cs + (size_t)seg * TCAP;
    int*   oi = ci + (size_t)seg * TCAP;
    for (int i = tid; i < nl; i += NT){ os[i] = lsc[i]; oi[i] = lidx[i]; }
}

// ---------------- per-batch exact top-K (LDS-resident radix + sort) ----------------

#define NT2 1024

__global__ __launch_bounds__(NT2) void select_k(
        const float* __restrict__ cs, const int* __restrict__ ci, const int* __restrict__ cnt,
        const float* __restrict__ points, int* __restrict__ sidx_g,
        float* __restrict__ out){
    __shared__ float lsc[NCAP];                  // 74 KB: all candidate scores, contiguous
    __shared__ unsigned long long keys[SELCAP];  // 16 KB
    __shared__ int hist[256];
    __shared__ int segc[64];
    __shared__ int pref[65];
    __shared__ int sidx[KK];
    __shared__ unsigned int sh_prefix;
    __shared__ int sh_kneed;
    __shared__ int selCnt;

    const int b = blockIdx.x, tid = threadIdx.x;

    if (tid < 64){ int c = cnt[b*64 + tid]; segc[tid] = (c > TCAP) ? TCAP : c; }
    __syncthreads();
    if (tid == 0){
        int s = 0;
        for (int i = 0; i < 64; ++i){ pref[i] = s; s += segc[i]; }
        pref[64] = s; selCnt = 0;
    }
    __syncthreads();
    const int n = pref[64];                      // <= 64*289 = 18496 = NCAP

    // stage all scores into contiguous LDS (binary search seg for each flat pos)
    for (int f = tid; f < n; f += NT2){
        int lo = 0, hi = 64;
        while (hi - lo > 1){ int mid = (lo + hi) >> 1; if (pref[mid] <= f) lo = mid; else hi = mid; }
        lsc[f] = cs[(size_t)(b*64 + lo) * TCAP + (f - pref[lo])];
    }
    __syncthreads();

    // exact K-th largest via 4x8-bit radix select on float bits (all scores > 0)
    unsigned int Tbits = 1u;
    if (n >= KK){
        unsigned int prefix = 0; int kneed = KK;
        for (int r = 0; r < 4; ++r){
            int shift = 24 - 8 * r;
            for (int i = tid; i < 256; i += NT2) hist[i] = 0;
            __syncthreads();
            for (int i = tid; i < n; i += NT2){
                unsigned int bits = __float_as_uint(lsc[i]);
                if (r == 0 || (bits >> (shift + 8)) == prefix)
                    atomicAdd(&hist[(bits >> shift) & 255], 1);
            }
            __syncthreads();
            if (tid == 0){
                int cum = 0, d = 255;
                for (; d >= 0; --d){ cum += hist[d]; if (cum >= kneed) break; }
                if (d < 0) d = 0;
                sh_kneed = kneed - (cum - hist[d]);
                sh_prefix = (prefix << 8) | (unsigned int)d;
            }
            __syncthreads();
            prefix = sh_prefix; kneed = sh_kneed;
            __syncthreads();
        }
        Tbits = prefix;
    }

    // collect candidates with score >= T (idx fetched from global on hit)
    for (int f = tid; f < n; f += NT2){
        unsigned int bits = __float_as_uint(lsc[f]);
        if (bits >= Tbits){
            int p = atomicAdd(&selCnt, 1);
            if (p < SELCAP){
                int lo = 0, hi = 64;
                while (hi - lo > 1){ int mid = (lo + hi) >> 1; if (pref[mid] <= f) lo = mid; else hi = mid; }
                int idx = ci[(size_t)(b*64 + lo) * TCAP + (f - pref[lo])];
                keys[p] = ((unsigned long long)bits << 32) | (unsigned int)(~idx);
            }
        }
    }
    __syncthreads();
    int ns = selCnt; if (ns > SELCAP) ns = SELCAP;
    int P2 = 2; while (P2 < ns) P2 <<= 1;
    for (int i = tid; i < P2; i += NT2) if (i >= ns) keys[i] = 0ull;
    __syncthreads();

    // bitonic sort descending by (score_bits, ~idx) => score desc, idx asc
    for (int k = 2; k <= P2; k <<= 1){
        for (int j = k >> 1; j > 0; j >>= 1){
            for (int i = tid; i < P2; i += NT2){
                int partner = i ^ j;
                if (partner > i){
                    unsigned long long a = keys[i], c = keys[partner];
                    bool asc = ((i & k) != 0);
                    if ((a < c) != asc){ keys[i] = c; keys[partner] = a; }
                }
            }
            __syncthreads();
        }
    }

    for (int k = tid; k < KK; k += NT2){
        int idx = 0;
        if (k < ns) idx = (int)(~(unsigned int)(keys[k] & 0xFFFFFFFFull));
        sidx[k] = idx;
    }
    __syncthreads();
    if (ns < KK && tid == 0){
        // fallback (unreachable with real data): top_k of flat==-1 region, index asc
        int fill = ns;
        for (int idx = 0; idx < HWW && fill < KK; ++idx){
            bool inCand = false;
            for (int s = 0; s < 64 && !inCand; ++s){
                const int* pi = ci + (size_t)(b*64 + s) * TCAP;
                int c = segc[s];
                for (int i = 0; i < c; ++i) if (pi[i] == idx){ inCand = true; break; }
            }
            if (!inCand) sidx[fill++] = idx;
        }
    }
    __syncthreads();

    // outputs: kpts (B,K,4) and pixels (B,K,2); sidx to global for gather_k
    const float* pb = points + (size_t)b * 4 * HWW;
    float* out0 = out + (size_t)b * KK * 4;
    float* out2 = out + (size_t)(BB * KK * 4 + BB * CC * KK) + (size_t)b * KK * 2;
    for (int k = tid; k < KK; k += NT2){
        int idx = sidx[k];
        sidx_g[b * KK + k] = idx;
        out0[k * 4 + 0] = pb[idx];
        out0[k * 4 + 1] = pb[HWW + idx];
        out0[k * 4 + 2] = 0.0f;
        out0[k * 4 + 3] = 1.0f;
        out2[k * 2 + 0] = (float)(idx >> 9);
        out2[k * 2 + 1] = (float)(idx & (WW - 1));
    }
}

// ---------------- full-chip scattered feature gather ----------------
// feas (B,C,K): 1024 blocks x 256 threads, one element each.
__global__ __launch_bounds__(256) void gather_k(const int* __restrict__ sidx_g,
                                                const float* __restrict__ feat,
                                                float* __restrict__ out){
    int g = blockIdx.x * 256 + threadIdx.x;      // 0 .. BB*CC*KK-1
    int b = g >> 16;                             // CC*KK = 65536
    int j = g & 65535;
    int c = j >> 9;
    int k = j & (KK - 1);
    int idx = sidx_g[b * KK + k];
    float* out1 = out + (size_t)(BB * KK * 4);
    out1[(size_t)b * CC * KK + j] = feat[(size_t)b * CC * HWW + (size_t)c * HWW + idx];
}

extern "C" void kernel_launch(void* const* d_in, const int* in_sizes, int n_in,
                              void* d_out, int out_size, void* d_ws, size_t ws_size,
                              hipStream_t stream) {
    const float* s    = (const float*)d_in[0];  // score_bev  (B,1,H,W)
    const float* feat = (const float*)d_in[1];  // feature_bev(B,C,H,W)
    const float* pts  = (const float*)d_in[2];  // points     (B,4,H,W)
    float* out = (float*)d_out;

    char* w = (char*)d_ws;
    float* cs  = (float*)w;  w += (size_t)BB * 64 * TCAP * 4;
    int*   ci  = (int*)w;    w += (size_t)BB * 64 * TCAP * 4;
    int*   cnt = (int*)w;    w += (size_t)BB * 64 * 4;
    int*   sidx_g = (int*)w; w += (size_t)BB * KK * 4;

    nms_fused_k<<<BB * 64, NT, 0, stream>>>(s, cs, ci, cnt);
    select_k<<<BB, NT2, 0, stream>>>(cs, ci, cnt, pts, sidx_g, out);
    gather_k<<<(BB * CC * KK) / 256, 256, 0, stream>>>(sidx_g, feat, out);
}

// Round 5
// 105.865 us; speedup vs baseline: 2.4120x; 1.0119x over previous
//
#include <hip/hip_runtime.h>
#include <stdint.h>
#include <math.h>

#define BB 4
#define HH 512
#define WW 512
#define HWW (HH*WW)      // 262144
#define CC 128
#define KK 512
#define SELCAP 2048
#define NCAP 18496       // 64 tiles * 289 max survivors (Chebyshev >=4 spacing)

#define TILE 64
#define HALO 15
#define TS 94            // TILE + 2*HALO
#define SWL 104          // LDS stride: 4-col front pad + 94 + tail, all f4-aligned
#define NT 1024
#define TCAP 512         // per-tile candidate slots (max real 289)

typedef unsigned int uint;
typedef unsigned long long u64;

__device__ __forceinline__ float4 ldsf4(const float* p, int o){ return *(const float4*)(p + o); }

// colmax over 7 rows, 4 lanes wide
#define COLMAX7V(src, o, cm)                                                  \
    { float4 c0=ldsf4(src,(o)-3*SWL), c1=ldsf4(src,(o)-2*SWL), c2=ldsf4(src,(o)-SWL), \
             c3=ldsf4(src,(o)),       c4=ldsf4(src,(o)+SWL),   c5=ldsf4(src,(o)+2*SWL), \
             c6=ldsf4(src,(o)+3*SWL);                                         \
      cm.x=fmaxf(fmaxf(fmaxf(c0.x,c1.x),fmaxf(c2.x,c3.x)),fmaxf(fmaxf(c4.x,c5.x),c6.x)); \
      cm.y=fmaxf(fmaxf(fmaxf(c0.y,c1.y),fmaxf(c2.y,c3.y)),fmaxf(fmaxf(c4.y,c5.y),c6.y)); \
      cm.z=fmaxf(fmaxf(fmaxf(c0.z,c1.z),fmaxf(c2.z,c3.z)),fmaxf(fmaxf(c4.z,c5.z),c6.z)); \
      cm.w=fmaxf(fmaxf(fmaxf(c0.w,c1.w),fmaxf(c2.w,c3.w)),fmaxf(fmaxf(c4.w,c5.w),c6.w)); }

// 7-wide sliding row max, 4 outputs per thread. v0..v11 = src[x0-4 .. x0+7]
#define ROWMAXV(dst, src, Y0, NROW, G0, NG)                                   \
    for (int i = tid; i < (NROW)*(NG); i += NT){                              \
        int y = (Y0) + i/(NG);                                                \
        int o = y*SWL + (G0) + 4*(i%(NG)) + 4;                                \
        float4 va = ldsf4(src, o-4), vb = ldsf4(src, o), vc = ldsf4(src, o+4);\
        float m2a=fmaxf(va.y,va.z), m2b=fmaxf(va.w,vb.x), m2c=fmaxf(vb.y,vb.z),\
              m2d=fmaxf(vb.w,vc.x), m2e=fmaxf(vc.y,vc.z);                     \
        float4 r;                                                             \
        r.x = fmaxf(fmaxf(m2a,m2b), fmaxf(m2c, vb.w));                        \
        r.y = fmaxf(fmaxf(va.z,m2b), fmaxf(m2c, m2d));                        \
        r.z = fmaxf(fmaxf(m2b,m2c), fmaxf(m2d, vc.y));                        \
        r.w = fmaxf(fmaxf(vb.x,m2c), fmaxf(m2d, m2e));                        \
        *(float4*)((dst) + o) = r;                                            \
    }                                                                         \
    __syncthreads();

// 7-wide sliding row OR on 0/1 bytes, 4 outputs per thread (uint packed)
#define ROWORV(dst, src, Y0, NROW, G0, NG)                                    \
    for (int i = tid; i < (NROW)*(NG); i += NT){                              \
        int y = (Y0) + i/(NG);                                                \
        int o = y*SWL + (G0) + 4*(i%(NG)) + 4;                                \
        uint u0 = *(const uint*)((src)+o-4), u1 = *(const uint*)((src)+o),    \
             u2 = *(const uint*)((src)+o+4);                                  \
        u64 lo = (u64)u0 | ((u64)u1 << 32);                                   \
        uint r = (uint)(lo>>8) | (uint)(lo>>16) | (uint)(lo>>24) | (uint)(lo>>32) \
               | ((uint)(lo>>40)|(u2<<24)) | ((uint)(lo>>48)|(u2<<16))        \
               | ((uint)(lo>>56)|(u2<<8));                                    \
        *(uint*)((dst)+o) = r;                                                \
    }                                                                         \
    __syncthreads();

// col-OR of T -> P; A = supp ? 0 : S (NaN halo passes through)
#define COLSUPPV(Y0, NROW, G0, NG)                                            \
    for (int i = tid; i < (NROW)*(NG); i += NT){                              \
        int y = (Y0) + i/(NG);                                                \
        int o = y*SWL + (G0) + 4*(i%(NG)) + 4;                                \
        uint v = *(const uint*)(T+o-3*SWL) | *(const uint*)(T+o-2*SWL)        \
               | *(const uint*)(T+o-SWL)   | *(const uint*)(T+o)              \
               | *(const uint*)(T+o+SWL)   | *(const uint*)(T+o+2*SWL)        \
               | *(const uint*)(T+o+3*SWL);                                   \
        *(uint*)(P + o) = v;                                                  \
        float4 s4 = ldsf4(S, o);                                              \
        float4 a;                                                             \
        a.x = (v & 0xffu)       ? 0.0f : s4.x;                                \
        a.y = (v & 0xff00u)     ? 0.0f : s4.y;                                \
        a.z = (v & 0xff0000u)   ? 0.0f : s4.z;                                \
        a.w = (v & 0xff000000u) ? 0.0f : s4.w;                                \
        *(float4*)(A + o) = a;                                                \
    }                                                                         \
    __syncthreads();

// One block = one 64x64 tile (+15 halo). 2-iteration NMS fully in LDS, vectorized 4x.
__global__ __launch_bounds__(NT) void nms_fused_k(const float* __restrict__ sc,
        float* __restrict__ cs, int* __restrict__ ci, int* __restrict__ cnt){
    __shared__ __align__(16) float S[TS*SWL];
    __shared__ __align__(16) float A[TS*SWL];
    __shared__ __align__(16) float Bf[TS*SWL];
    __shared__ __align__(16) unsigned char M[TS*SWL];
    __shared__ __align__(16) unsigned char T[TS*SWL];
    __shared__ __align__(16) unsigned char P[TS*SWL];
    __shared__ float lsc[TCAP];
    __shared__ int   lidx[TCAP];
    __shared__ int   lcnt;

    const int tid = threadIdx.x;
    const int bb = blockIdx.x >> 6;          // batch
    const int t  = blockIdx.x & 63;
    const int ty = t >> 3, tx = t & 7;
    const int oy = ty * TILE - HALO, ox = tx * TILE - HALO;
    const float* sb = sc + (size_t)bb * HWW;
    const float QNAN = __int_as_float(0x7fc00000);

    if (tid == 0) lcnt = 0;

    // load: image col x-4; out-of-image = NaN (acts as -inf pad for fmax, fails all ==)
    for (int i = tid; i < TS*SWL; i += NT){
        int y = i / SWL, x = i - y*SWL;
        int gy = oy + y, gx = ox + x - 4;
        float v = QNAN;
        if ((unsigned)gy < (unsigned)HH && (unsigned)gx < (unsigned)WW)
            v = sb[(gy << 9) + gx];
        S[i] = v;
    }
    __syncthreads();

    // ---- M0 = (s == pool7(s)) ----
    ROWMAXV(A, S, 0, 94, 0, 23)                       // valid x [3,90]
    for (int i = tid; i < 88*23; i += NT){            // y [3,90], x groups [0,88]
        int y = 3 + i/23;
        int o = y*SWL + 4*(i%23) + 4;
        float4 cm; COLMAX7V(A, o, cm);
        float4 s4 = ldsf4(S, o);
        uint m = (s4.x==cm.x ?1u:0u) | (s4.y==cm.y ?0x100u:0u)
               | (s4.z==cm.z ?0x10000u:0u) | (s4.w==cm.w ?0x1000000u:0u);
        *(uint*)(M + o) = m;
    }
    __syncthreads();

    // ---- iteration 1 ----
    ROWORV(T, M, 3, 88, 4, 21)                        // valid x [6,87]
    COLSUPPV(6, 82, 4, 21)                            // P=supp1, A=ss1, valid [6,87]
    ROWMAXV(Bf, A, 6, 82, 8, 20)                      // valid x [9,84]
    for (int i = tid; i < 76*20; i += NT){            // update: y [9,84]
        int y = 9 + i/20;
        int o = y*SWL + 8 + 4*(i%20) + 4;
        float4 cm; COLMAX7V(Bf, o, cm);
        float4 a4 = ldsf4(A, o);
        uint p4 = *(const uint*)(P+o);
        uint nm = (a4.x==cm.x ?1u:0u)|(a4.y==cm.y ?0x100u:0u)
                | (a4.z==cm.z ?0x10000u:0u)|(a4.w==cm.w ?0x1000000u:0u);
        uint m4 = *(const uint*)(M+o);
        *(uint*)(M+o) = m4 | (nm & ~p4);
    }
    __syncthreads();

    // ---- iteration 2 ----
    ROWORV(T, M, 9, 76, 12, 18)                       // valid x [12,81]
    COLSUPPV(12, 70, 12, 18)                          // P=supp2, A=ss2
    ROWMAXV(Bf, A, 12, 70, 12, 17)                    // valid x [15,78]

    // ---- final mask + per-block compaction (y,x in [15,78]) ----
    for (int i = tid; i < 64*17; i += NT){
        int y = 15 + i/17;
        int xg = 12 + 4*(i%17);
        int o = y*SWL + xg + 4;
        float4 cm; COLMAX7V(Bf, o, cm);
        float4 a4 = ldsf4(A, o), s4 = ldsf4(S, o);
        uint p4 = *(const uint*)(P+o), m4 = *(const uint*)(M+o);
        float sa[4] = {s4.x, s4.y, s4.z, s4.w};
        float aa[4] = {a4.x, a4.y, a4.z, a4.w};
        float ca[4] = {cm.x, cm.y, cm.z, cm.w};
        #pragma unroll
        for (int j = 0; j < 4; ++j){
            int x = xg + j;
            bool fm = ((m4 >> (8*j)) & 1u) || ((aa[j]==ca[j]) && !((p4 >> (8*j)) & 1u));
            if ((unsigned)(x - 15) < 64u && fm && sa[j] > 0.0f){
                int p = atomicAdd(&lcnt, 1);
                if (p < TCAP){ lsc[p] = sa[j]; lidx[p] = ((oy+y) << 9) + (ox+x); }
            }
        }
    }
    __syncthreads();

    int nl = lcnt; if (nl > TCAP) nl = TCAP;
    const int seg = bb * 64 + t;
    if (tid == 0) cnt[seg] = nl;
    float* os = cs + (size_t)seg * TCAP;
    int*   oi = ci + (size_t)seg * TCAP;
    for (int i = tid; i < nl; i += NT){ os[i] = lsc[i]; oi[i] = lidx[i]; }
}

// ---------------- per-batch exact top-K (LDS-resident radix + sort) ----------------

#define NT2 1024

__global__ __launch_bounds__(NT2) void select_k(
        const float* __restrict__ cs, const int* __restrict__ ci, const int* __restrict__ cnt,
        const float* __restrict__ points, int* __restrict__ sidx_g,
        float* __restrict__ out){
    __shared__ float lsc[NCAP];
    __shared__ unsigned long long keys[SELCAP];
    __shared__ int hist[256];
    __shared__ int segc[64];
    __shared__ int pref[65];
    __shared__ int sidx[KK];
    __shared__ unsigned int sh_prefix;
    __shared__ int sh_kneed;
    __shared__ int selCnt;

    const int b = blockIdx.x, tid = threadIdx.x;

    if (tid < 64){ int c = cnt[b*64 + tid]; segc[tid] = (c > TCAP) ? TCAP : c; }
    __syncthreads();
    if (tid == 0){
        int s = 0;
        for (int i = 0; i < 64; ++i){ pref[i] = s; s += segc[i]; }
        pref[64] = s; selCnt = 0;
    }
    __syncthreads();
    const int n = pref[64];

    for (int f = tid; f < n; f += NT2){
        int lo = 0, hi = 64;
        while (hi - lo > 1){ int mid = (lo + hi) >> 1; if (pref[mid] <= f) lo = mid; else hi = mid; }
        lsc[f] = cs[(size_t)(b*64 + lo) * TCAP + (f - pref[lo])];
    }
    __syncthreads();

    unsigned int Tbits = 1u;
    if (n >= KK){
        unsigned int prefix = 0; int kneed = KK;
        for (int r = 0; r < 4; ++r){
            int shift = 24 - 8 * r;
            for (int i = tid; i < 256; i += NT2) hist[i] = 0;
            __syncthreads();
            for (int i = tid; i < n; i += NT2){
                unsigned int bits = __float_as_uint(lsc[i]);
                if (r == 0 || (bits >> (shift + 8)) == prefix)
                    atomicAdd(&hist[(bits >> shift) & 255], 1);
            }
            __syncthreads();
            if (tid == 0){
                int cum = 0, d = 255;
                for (; d >= 0; --d){ cum += hist[d]; if (cum >= kneed) break; }
                if (d < 0) d = 0;
                sh_kneed = kneed - (cum - hist[d]);
                sh_prefix = (prefix << 8) | (unsigned int)d;
            }
            __syncthreads();
            prefix = sh_prefix; kneed = sh_kneed;
            __syncthreads();
        }
        Tbits = prefix;
    }

    for (int f = tid; f < n; f += NT2){
        unsigned int bits = __float_as_uint(lsc[f]);
        if (bits >= Tbits){
            int p = atomicAdd(&selCnt, 1);
            if (p < SELCAP){
                int lo = 0, hi = 64;
                while (hi - lo > 1){ int mid = (lo + hi) >> 1; if (pref[mid] <= f) lo = mid; else hi = mid; }
                int idx = ci[(size_t)(b*64 + lo) * TCAP + (f - pref[lo])];
                keys[p] = ((unsigned long long)bits << 32) | (unsigned int)(~idx);
            }
        }
    }
    __syncthreads();
    int ns = selCnt; if (ns > SELCAP) ns = SELCAP;
    int P2 = 2; while (P2 < ns) P2 <<= 1;
    for (int i = tid; i < P2; i += NT2) if (i >= ns) keys[i] = 0ull;
    __syncthreads();

    for (int k = 2; k <= P2; k <<= 1){
        for (int j = k >> 1; j > 0; j >>= 1){
            for (int i = tid; i < P2; i += NT2){
                int partner = i ^ j;
                if (partner > i){
                    unsigned long long a = keys[i], c = keys[partner];
                    bool asc = ((i & k) != 0);
                    if ((a < c) != asc){ keys[i] = c; keys[partner] = a; }
                }
            }
            __syncthreads();
        }
    }

    for (int k = tid; k < KK; k += NT2){
        int idx = 0;
        if (k < ns) idx = (int)(~(unsigned int)(keys[k] & 0xFFFFFFFFull));
        sidx[k] = idx;
    }
    __syncthreads();
    if (ns < KK && tid == 0){
        int fill = ns;
        for (int idx = 0; idx < HWW && fill < KK; ++idx){
            bool inCand = false;
            for (int s = 0; s < 64 && !inCand; ++s){
                const int* pi = ci + (size_t)(b*64 + s) * TCAP;
                int c = segc[s];
                for (int i = 0; i < c; ++i) if (pi[i] == idx){ inCand = true; break; }
            }
            if (!inCand) sidx[fill++] = idx;
        }
    }
    __syncthreads();

    const float* pb = points + (size_t)b * 4 * HWW;
    float* out0 = out + (size_t)b * KK * 4;
    float* out2 = out + (size_t)(BB * KK * 4 + BB * CC * KK) + (size_t)b * KK * 2;
    for (int k = tid; k < KK; k += NT2){
        int idx = sidx[k];
        sidx_g[b * KK + k] = idx;
        out0[k * 4 + 0] = pb[idx];
        out0[k * 4 + 1] = pb[HWW + idx];
        out0[k * 4 + 2] = 0.0f;
        out0[k * 4 + 3] = 1.0f;
        out2[k * 2 + 0] = (float)(idx >> 9);
        out2[k * 2 + 1] = (float)(idx & (WW - 1));
    }
}

// ---------------- full-chip scattered feature gather ----------------
__global__ __launch_bounds__(256) void gather_k(const int* __restrict__ sidx_g,
                                                const float* __restrict__ feat,
                                                float* __restrict__ out){
    int g = blockIdx.x * 256 + threadIdx.x;
    int b = g >> 16;                             // CC*KK = 65536
    int j = g & 65535;
    int c = j >> 9;
    int k = j & (KK - 1);
    int idx = sidx_g[b * KK + k];
    float* out1 = out + (size_t)(BB * KK * 4);
    out1[(size_t)b * CC * KK + j] = feat[(size_t)b * CC * HWW + (size_t)c * HWW + idx];
}

extern "C" void kernel_launch(void* const* d_in, const int* in_sizes, int n_in,
                              void* d_out, int out_size, void* d_ws, size_t ws_size,
                              hipStream_t stream) {
    const float* s    = (const float*)d_in[0];  // score_bev  (B,1,H,W)
    const float* feat = (const float*)d_in[1];  // feature_bev(B,C,H,W)
    const float* pts  = (const float*)d_in[2];  // points     (B,4,H,W)
    float* out = (float*)d_out;

    char* w = (char*)d_ws;
    float* cs  = (float*)w;  w += (size_t)BB * 64 * TCAP * 4;
    int*   ci  = (int*)w;    w += (size_t)BB * 64 * TCAP * 4;
    int*   cnt = (int*)w;    w += (size_t)BB * 64 * 4;
    int*   sidx_g = (int*)w; w += (size_t)BB * KK * 4;

    nms_fused_k<<<BB * 64, NT, 0, stream>>>(s, cs, ci, cnt);
    select_k<<<BB, NT2, 0, stream>>>(cs, ci, cnt, pts, sidx_g, out);
    gather_k<<<(BB * CC * KK) / 256, 256, 0, stream>>>(sidx_g, feat, out);
}

// Round 6
// 72.228 us; speedup vs baseline: 3.5353x; 1.4657x over previous
//
#include <hip/hip_runtime.h>
#include <stdint.h>
#include <math.h>

#define BB 4
#define HH 512
#define WW 512
#define HWW (HH*WW)      // 262144
#define CC 128
#define KK 512
#define SELCAP 2048
#define NCAP 18496       // 64 tiles * 289 max survivors (Chebyshev >=4 spacing)

#define TILE 64
#define HALO 15
#define TS 94            // TILE + 2*HALO
#define SWL 104          // LDS stride: 4-col front pad + 94 + tail, all f4-aligned
#define NT 1024
#define TCAP 512         // per-tile candidate slots (max real 289)

typedef unsigned int uint;
typedef unsigned long long u64;

__device__ __forceinline__ float4 ldsf4(const float* p, int o){ return *(const float4*)(p + o); }

// colmax over 7 rows, 4 lanes wide
#define COLMAX7V(src, o, cm)                                                  \
    { float4 c0=ldsf4(src,(o)-3*SWL), c1=ldsf4(src,(o)-2*SWL), c2=ldsf4(src,(o)-SWL), \
             c3=ldsf4(src,(o)),       c4=ldsf4(src,(o)+SWL),   c5=ldsf4(src,(o)+2*SWL), \
             c6=ldsf4(src,(o)+3*SWL);                                         \
      cm.x=fmaxf(fmaxf(fmaxf(c0.x,c1.x),fmaxf(c2.x,c3.x)),fmaxf(fmaxf(c4.x,c5.x),c6.x)); \
      cm.y=fmaxf(fmaxf(fmaxf(c0.y,c1.y),fmaxf(c2.y,c3.y)),fmaxf(fmaxf(c4.y,c5.y),c6.y)); \
      cm.z=fmaxf(fmaxf(fmaxf(c0.z,c1.z),fmaxf(c2.z,c3.z)),fmaxf(fmaxf(c4.z,c5.z),c6.z)); \
      cm.w=fmaxf(fmaxf(fmaxf(c0.w,c1.w),fmaxf(c2.w,c3.w)),fmaxf(fmaxf(c4.w,c5.w),c6.w)); }

// 7-wide sliding row max, 4 outputs per thread
#define ROWMAXV(dst, src, Y0, NROW, G0, NG)                                   \
    for (int i = tid; i < (NROW)*(NG); i += NT){                              \
        int y = (Y0) + i/(NG);                                                \
        int o = y*SWL + (G0) + 4*(i%(NG)) + 4;                                \
        float4 va = ldsf4(src, o-4), vb = ldsf4(src, o), vc = ldsf4(src, o+4);\
        float m2a=fmaxf(va.y,va.z), m2b=fmaxf(va.w,vb.x), m2c=fmaxf(vb.y,vb.z),\
              m2d=fmaxf(vb.w,vc.x), m2e=fmaxf(vc.y,vc.z);                     \
        float4 r;                                                             \
        r.x = fmaxf(fmaxf(m2a,m2b), fmaxf(m2c, vb.w));                        \
        r.y = fmaxf(fmaxf(va.z,m2b), fmaxf(m2c, m2d));                        \
        r.z = fmaxf(fmaxf(m2b,m2c), fmaxf(m2d, vc.y));                        \
        r.w = fmaxf(fmaxf(vb.x,m2c), fmaxf(m2d, m2e));                        \
        *(float4*)((dst) + o) = r;                                            \
    }                                                                         \
    __syncthreads();

// 7-wide sliding row OR on 0/1 bytes, 4 outputs per thread (uint packed)
#define ROWORV(dst, src, Y0, NROW, G0, NG)                                    \
    for (int i = tid; i < (NROW)*(NG); i += NT){                              \
        int y = (Y0) + i/(NG);                                                \
        int o = y*SWL + (G0) + 4*(i%(NG)) + 4;                                \
        uint u0 = *(const uint*)((src)+o-4), u1 = *(const uint*)((src)+o),    \
             u2 = *(const uint*)((src)+o+4);                                  \
        u64 lo = (u64)u0 | ((u64)u1 << 32);                                   \
        uint r = (uint)(lo>>8) | (uint)(lo>>16) | (uint)(lo>>24) | (uint)(lo>>32) \
               | ((uint)(lo>>40)|(u2<<24)) | ((uint)(lo>>48)|(u2<<16))        \
               | ((uint)(lo>>56)|(u2<<8));                                    \
        *(uint*)((dst)+o) = r;                                                \
    }                                                                         \
    __syncthreads();

// col-OR of T -> P; A = supp ? 0 : S (NaN halo passes through)
#define COLSUPPV(Y0, NROW, G0, NG)                                            \
    for (int i = tid; i < (NROW)*(NG); i += NT){                              \
        int y = (Y0) + i/(NG);                                                \
        int o = y*SWL + (G0) + 4*(i%(NG)) + 4;                                \
        uint v = *(const uint*)(T+o-3*SWL) | *(const uint*)(T+o-2*SWL)        \
               | *(const uint*)(T+o-SWL)   | *(const uint*)(T+o)              \
               | *(const uint*)(T+o+SWL)   | *(const uint*)(T+o+2*SWL)        \
               | *(const uint*)(T+o+3*SWL);                                   \
        *(uint*)(P + o) = v;                                                  \
        float4 s4 = ldsf4(S, o);                                              \
        float4 a;                                                             \
        a.x = (v & 0xffu)       ? 0.0f : s4.x;                                \
        a.y = (v & 0xff00u)     ? 0.0f : s4.y;                                \
        a.z = (v & 0xff0000u)   ? 0.0f : s4.z;                                \
        a.w = (v & 0xff000000u) ? 0.0f : s4.w;                                \
        *(float4*)(A + o) = a;                                                \
    }                                                                         \
    __syncthreads();

// One block = one 64x64 tile (+15 halo). 2-iteration NMS fully in LDS, vectorized 4x.
__global__ __launch_bounds__(NT) void nms_fused_k(const float* __restrict__ sc,
        float* __restrict__ cs, int* __restrict__ ci, int* __restrict__ cnt){
    __shared__ __align__(16) float S[TS*SWL];
    __shared__ __align__(16) float A[TS*SWL];
    __shared__ __align__(16) float Bf[TS*SWL];
    __shared__ __align__(16) unsigned char M[TS*SWL];
    __shared__ __align__(16) unsigned char T[TS*SWL];
    __shared__ __align__(16) unsigned char P[TS*SWL];
    __shared__ float lsc[TCAP];
    __shared__ int   lidx[TCAP];
    __shared__ int   lcnt;

    const int tid = threadIdx.x;
    const int bb = blockIdx.x >> 6;          // batch
    const int t  = blockIdx.x & 63;
    const int ty = t >> 3, tx = t & 7;
    const int oy = ty * TILE - HALO, ox = tx * TILE - HALO;
    const float* sb = sc + (size_t)bb * HWW;
    const float QNAN = __int_as_float(0x7fc00000);

    if (tid == 0) lcnt = 0;

    // load: image col x-4; out-of-image = NaN (acts as -inf pad for fmax, fails all ==)
    for (int i = tid; i < TS*SWL; i += NT){
        int y = i / SWL, x = i - y*SWL;
        int gy = oy + y, gx = ox + x - 4;
        float v = QNAN;
        if ((unsigned)gy < (unsigned)HH && (unsigned)gx < (unsigned)WW)
            v = sb[(gy << 9) + gx];
        S[i] = v;
    }
    __syncthreads();

    // ---- M0 = (s == pool7(s)) ----
    ROWMAXV(A, S, 0, 94, 0, 23)                       // valid x [3,90]
    for (int i = tid; i < 88*23; i += NT){            // y [3,90]
        int y = 3 + i/23;
        int o = y*SWL + 4*(i%23) + 4;
        float4 cm; COLMAX7V(A, o, cm);
        float4 s4 = ldsf4(S, o);
        uint m = (s4.x==cm.x ?1u:0u) | (s4.y==cm.y ?0x100u:0u)
               | (s4.z==cm.z ?0x10000u:0u) | (s4.w==cm.w ?0x1000000u:0u);
        *(uint*)(M + o) = m;
    }
    __syncthreads();

    // ---- iteration 1 ----
    ROWORV(T, M, 3, 88, 4, 21)                        // valid x [6,87]
    COLSUPPV(6, 82, 4, 21)                            // P=supp1, A=ss1
    ROWMAXV(Bf, A, 6, 82, 8, 20)                      // valid x [9,84]
    for (int i = tid; i < 76*20; i += NT){            // update
        int y = 9 + i/20;
        int o = y*SWL + 8 + 4*(i%20) + 4;
        float4 cm; COLMAX7V(Bf, o, cm);
        float4 a4 = ldsf4(A, o);
        uint p4 = *(const uint*)(P+o);
        uint nm = (a4.x==cm.x ?1u:0u)|(a4.y==cm.y ?0x100u:0u)
                | (a4.z==cm.z ?0x10000u:0u)|(a4.w==cm.w ?0x1000000u:0u);
        uint m4 = *(const uint*)(M+o);
        *(uint*)(M+o) = m4 | (nm & ~p4);
    }
    __syncthreads();

    // ---- iteration 2 ----
    ROWORV(T, M, 9, 76, 12, 18)                       // valid x [12,81]
    COLSUPPV(12, 70, 12, 18)                          // P=supp2, A=ss2
    ROWMAXV(Bf, A, 12, 70, 12, 17)                    // valid x [15,78]

    // ---- final mask + per-block compaction ----
    for (int i = tid; i < 64*17; i += NT){
        int y = 15 + i/17;
        int xg = 12 + 4*(i%17);
        int o = y*SWL + xg + 4;
        float4 cm; COLMAX7V(Bf, o, cm);
        float4 a4 = ldsf4(A, o), s4 = ldsf4(S, o);
        uint p4 = *(const uint*)(P+o), m4 = *(const uint*)(M+o);
        float sa[4] = {s4.x, s4.y, s4.z, s4.w};
        float aa[4] = {a4.x, a4.y, a4.z, a4.w};
        float ca[4] = {cm.x, cm.y, cm.z, cm.w};
        #pragma unroll
        for (int j = 0; j < 4; ++j){
            int x = xg + j;
            bool fm = ((m4 >> (8*j)) & 1u) || ((aa[j]==ca[j]) && !((p4 >> (8*j)) & 1u));
            if ((unsigned)(x - 15) < 64u && fm && sa[j] > 0.0f){
                int p = atomicAdd(&lcnt, 1);
                if (p < TCAP){ lsc[p] = sa[j]; lidx[p] = ((oy+y) << 9) + (ox+x); }
            }
        }
    }
    __syncthreads();

    int nl = lcnt; if (nl > TCAP) nl = TCAP;
    const int seg = bb * 64 + t;
    if (tid == 0) cnt[seg] = nl;
    float* os = cs + (size_t)seg * TCAP;
    int*   oi = ci + (size_t)seg * TCAP;
    for (int i = tid; i < nl; i += NT){ os[i] = lsc[i]; oi[i] = lidx[i]; }
}

// ---------------- per-batch exact top-K: contention-free radix + rank-by-count ----------------

#define NT2 1024
#define NW2 16            // waves per block

__global__ __launch_bounds__(NT2) void select_k(
        const float* __restrict__ cs, const int* __restrict__ ci, const int* __restrict__ cnt,
        const float* __restrict__ points, int* __restrict__ sidx_g,
        float* __restrict__ out){
    __shared__ float lsc[NCAP];                  // 74 KB
    __shared__ u64   keys[SELCAP + 4];           // 16 KB (+pad for unroll tail)
    __shared__ int   whist[NW2][257];            // 16.4 KB, +1 pad decorrelates banks
    __shared__ int   hist[256];
    __shared__ int   segc[64];
    __shared__ int   pref[65];
    __shared__ int   sidx[KK];
    __shared__ uint  sh_prefix;
    __shared__ int   sh_kneed;
    __shared__ int   selCnt;

    const int b = blockIdx.x, tid = threadIdx.x;
    const int wv = tid >> 6, lane = tid & 63;

    if (tid < 64){ int c = cnt[b*64 + tid]; segc[tid] = (c > TCAP) ? TCAP : c; }
    __syncthreads();
    if (tid == 0){
        int s = 0;
        for (int i = 0; i < 64; ++i){ pref[i] = s; s += segc[i]; }
        pref[64] = s; selCnt = 0;
    }
    __syncthreads();
    const int n = pref[64];

    // stage all scores into contiguous LDS (binary search seg per flat pos)
    for (int f = tid; f < n; f += NT2){
        int lo = 0, hi = 64;
        while (hi - lo > 1){ int mid = (lo + hi) >> 1; if (pref[mid] <= f) lo = mid; else hi = mid; }
        lsc[f] = cs[(size_t)(b*64 + lo) * TCAP + (f - pref[lo])];
    }
    __syncthreads();

    // exact K-th largest: 4x8-bit radix, per-wave hist (kills same-address contention),
    // wave-0 shfl suffix-scan digit pick (kills tid0 serial scan)
    uint Tbits = 1u;
    if (n >= KK){
        uint prefix = 0; int kneed = KK;
        for (int r = 0; r < 4; ++r){
            const int shift = 24 - 8 * r;
            for (int i = tid; i < NW2*257; i += NT2) ((int*)whist)[i] = 0;
            __syncthreads();
            for (int i = tid; i < n; i += NT2){
                uint bits = __float_as_uint(lsc[i]);
                if (r == 0 || (bits >> (shift + 8)) == prefix)
                    atomicAdd(&whist[wv][(bits >> shift) & 255], 1);
            }
            __syncthreads();
            if (tid < 256){
                int s = 0;
                #pragma unroll
                for (int w2 = 0; w2 < NW2; ++w2) s += whist[w2][tid];
                hist[tid] = s;
            }
            __syncthreads();
            if (tid < 64){
                int b0 = hist[4*lane], b1 = hist[4*lane+1], b2 = hist[4*lane+2], b3 = hist[4*lane+3];
                int gs = b0 + b1 + b2 + b3;
                int suf = gs;
                #pragma unroll
                for (int off = 1; off < 64; off <<= 1){
                    int v = __shfl_down(suf, off);
                    if (lane + off < 64) suf += v;
                }                                    // suf = cumFromTop(4*lane)
                u64 mask = __ballot(suf >= kneed);   // nonzero: suf(0)=total>=kneed
                int lstar = 63 - __clzll(mask);
                if (lane == lstar){
                    int bins[4] = {b0, b1, b2, b3};
                    int cum = suf - gs;              // cumFromTop(4*lane+4)
                    int d = 3;
                    for (; d > 0; --d){ cum += bins[d]; if (cum >= kneed) break; }
                    if (d == 0) cum += bins[0];
                    sh_kneed = kneed - (cum - bins[d]);
                    sh_prefix = (prefix << 8) | (uint)(4*lane + d);
                }
            }
            __syncthreads();
            prefix = sh_prefix; kneed = sh_kneed;
            __syncthreads();
        }
        Tbits = prefix;
    }

    // collect candidates with score >= T
    for (int f = tid; f < n; f += NT2){
        uint bits = __float_as_uint(lsc[f]);
        if (bits >= Tbits){
            int p = atomicAdd(&selCnt, 1);
            if (p < SELCAP){
                int lo = 0, hi = 64;
                while (hi - lo > 1){ int mid = (lo + hi) >> 1; if (pref[mid] <= f) lo = mid; else hi = mid; }
                int idx = ci[(size_t)(b*64 + lo) * TCAP + (f - pref[lo])];
                keys[p] = ((u64)bits << 32) | (uint)(~idx);
            }
        }
    }
    __syncthreads();
    int ns = selCnt; if (ns > SELCAP) ns = SELCAP;
    int npad = (ns + 3) & ~3;
    for (int i = tid; i < npad + 4; i += NT2) if (i >= ns) keys[i] = 0ull;
    __syncthreads();

    // rank-by-count: rank = #{keys strictly greater}; keys unique (idx distinct).
    // All threads read keys[j] in lockstep -> LDS broadcast, zero barriers.
    for (int i = tid; i < ns; i += NT2){
        u64 my = keys[i];
        int rank = 0;
        #pragma unroll 4
        for (int j = 0; j < npad; ++j) rank += (keys[j] > my) ? 1 : 0;
        if (rank < KK) sidx[rank] = (int)(~(uint)(my & 0xFFFFFFFFull));
    }
    __syncthreads();

    if (ns < KK && tid == 0){
        // fallback (unreachable with real data): fill with smallest absent indices
        int fill = ns;
        for (int idx = 0; idx < HWW && fill < KK; ++idx){
            bool inCand = false;
            for (int s = 0; s < 64 && !inCand; ++s){
                const int* pi = ci + (size_t)(b*64 + s) * TCAP;
                int c = segc[s];
                for (int i = 0; i < c; ++i) if (pi[i] == idx){ inCand = true; break; }
            }
            if (!inCand) sidx[fill++] = idx;
        }
    }
    __syncthreads();

    // outputs: kpts (B,K,4), pixels (B,K,2); sidx to global for gather_k
    const float* pb = points + (size_t)b * 4 * HWW;
    float* out0 = out + (size_t)b * KK * 4;
    float* out2 = out + (size_t)(BB * KK * 4 + BB * CC * KK) + (size_t)b * KK * 2;
    for (int k = tid; k < KK; k += NT2){
        int idx = sidx[k];
        sidx_g[b * KK + k] = idx;
        out0[k * 4 + 0] = pb[idx];
        out0[k * 4 + 1] = pb[HWW + idx];
        out0[k * 4 + 2] = 0.0f;
        out0[k * 4 + 3] = 1.0f;
        out2[k * 2 + 0] = (float)(idx >> 9);
        out2[k * 2 + 1] = (float)(idx & (WW - 1));
    }
}

// ---------------- full-chip scattered feature gather ----------------
__global__ __launch_bounds__(256) void gather_k(const int* __restrict__ sidx_g,
                                                const float* __restrict__ feat,
                                                float* __restrict__ out){
    int g = blockIdx.x * 256 + threadIdx.x;
    int b = g >> 16;                             // CC*KK = 65536
    int j = g & 65535;
    int c = j >> 9;
    int k = j & (KK - 1);
    int idx = sidx_g[b * KK + k];
    float* out1 = out + (size_t)(BB * KK * 4);
    out1[(size_t)b * CC * KK + j] = feat[(size_t)b * CC * HWW + (size_t)c * HWW + idx];
}

extern "C" void kernel_launch(void* const* d_in, const int* in_sizes, int n_in,
                              void* d_out, int out_size, void* d_ws, size_t ws_size,
                              hipStream_t stream) {
    const float* s    = (const float*)d_in[0];  // score_bev  (B,1,H,W)
    const float* feat = (const float*)d_in[1];  // feature_bev(B,C,H,W)
    const float* pts  = (const float*)d_in[2];  // points     (B,4,H,W)
    float* out = (float*)d_out;

    char* w = (char*)d_ws;
    float* cs  = (float*)w;  w += (size_t)BB * 64 * TCAP * 4;
    int*   ci  = (int*)w;    w += (size_t)BB * 64 * TCAP * 4;
    int*   cnt = (int*)w;    w += (size_t)BB * 64 * 4;
    int*   sidx_g = (int*)w; w += (size_t)BB * KK * 4;

    nms_fused_k<<<BB * 64, NT, 0, stream>>>(s, cs, ci, cnt);
    select_k<<<BB, NT2, 0, stream>>>(cs, ci, cnt, pts, sidx_g, out);
    gather_k<<<(BB * CC * KK) / 256, 256, 0, stream>>>(sidx_g, feat, out);
}